// Round 6
// baseline (271.562 us; speedup 1.0000x reference)
//
#include <hip/hip_runtime.h>

// ---------------- problem constants ----------------
#define B_    4
#define L_    1370
#define NH_   16
#define D_    64
#define HID_  1024
#define M_    (B_ * L_)        // 5480
#define LPAD  1408             // padded rows/cols per head (multiple of 128)

// workspace layout (bf16 elements)
#define XB_OFF  0u                      // X bf16 [M_][1024]        = 5,611,520
#define WB_OFF  5611520u                // Wq|Wk|Wv bf16            = 3,145,728
#define QW_OFF  8757248u                // q  [bh][LPAD][64]        = 5,767,168
#define KW_OFF  14524416u               // k  [bh][LPAD][64]        = 5,767,168
#define VT_OFF  20291584u               // v^T [bh][64][LPAD]       = 5,767,168
// total 26,058,752 el = 52.1 MB

typedef __attribute__((ext_vector_type(8))) short bf16x8;
typedef __attribute__((ext_vector_type(4))) short bf16x4;
typedef __attribute__((ext_vector_type(4))) float f32x4;
typedef __attribute__((ext_vector_type(2))) unsigned int u32x2;

#define LOG2E   1.44269504089f
#define QSCALE  0.18033688011f    // 0.125 * log2(e), folded into Q at GEMM
#define SOFT_M2 14.4269504089f    // 10 * log2(e): exp(s-10) == exp2(qk' - SOFT_M2)

__device__ __forceinline__ unsigned short f2bf(float f) {
  unsigned int u = __builtin_bit_cast(unsigned int, f);
  u += 0x7FFFu + ((u >> 16) & 1u);
  return (unsigned short)(u >> 16);
}

__device__ __forceinline__ float fexp2(float x) {
#if __has_builtin(__builtin_amdgcn_exp2f)
  return __builtin_amdgcn_exp2f(x);
#else
  return exp2f(x);
#endif
}

__device__ __forceinline__ unsigned int pkbf(float a, float b) {
#if __has_builtin(__builtin_amdgcn_cvt_pk_bf16_f32)
  auto r = __builtin_amdgcn_cvt_pk_bf16_f32(a, b);   // a -> low16, b -> high16
  return __builtin_bit_cast(unsigned int, r);
#else
  return (unsigned int)f2bf(a) | ((unsigned int)f2bf(b) << 16);
#endif
}

// async global->LDS, 16B per lane; LDS dest = wave-uniform base + lane*16
#define GLOAD16(gp, lp)                                                    \
  __builtin_amdgcn_global_load_lds(                                        \
      (const __attribute__((address_space(1))) unsigned int*)(gp),         \
      (__attribute__((address_space(3))) unsigned int*)(lp), 16, 0, 0)

// ---------------- fp32 -> bf16 (X + Wq + Wk + Wv) ----------------
#define XN4 ((M_ * HID_) / 4)
#define WN4 ((HID_ * HID_) / 4)
#define TOT4 (XN4 + 3 * WN4)

__global__ void cvt_all(const float* __restrict__ hs,
                        const float* __restrict__ Wq,
                        const float* __restrict__ Wk,
                        const float* __restrict__ Wv,
                        unsigned short* __restrict__ ws) {
  int i4 = blockIdx.x * 256 + threadIdx.x;
  if (i4 >= TOT4) return;
  const float* src;
  unsigned short* dst;
  if (i4 < XN4) {
    src = hs + (size_t)i4 * 4;
    dst = ws + XB_OFF + (size_t)i4 * 4;
  } else {
    int j = i4 - XN4;
    int w = j >> 18;
    int jj = j & (WN4 - 1);
    src = (w == 0 ? Wq : w == 1 ? Wk : Wv) + (size_t)jj * 4;
    dst = ws + WB_OFF + (size_t)w * (HID_ * HID_) + (size_t)jj * 4;
  }
  float4 v = *(const float4*)src;
  bf16x4 o;
  o[0] = (short)f2bf(v.x); o[1] = (short)f2bf(v.y);
  o[2] = (short)f2bf(v.z); o[3] = (short)f2bf(v.w);
  *(bf16x4*)dst = o;
}

// ---------------- QKV projection GEMM ----------------
// grid (44 = 4 batches x 11 m-blocks, 8 n-blocks, 3 weights), 256 threads.
// 128x128 tile, BK=128 (8 k-iters: halves the barrier/vmcnt-drain count —
// we are reg-capped at 2 blocks/CU so the 64 KB LDS is free).
// LDS [row][128] unpadded, XOR swizzle g'=g^(row&15) over 16 groups of 8.
__global__ __launch_bounds__(256)
void qkv_gemm(const unsigned short* __restrict__ XB,
              const unsigned short* __restrict__ WB,
              const float* __restrict__ bq,
              const float* __restrict__ bk,
              const float* __restrict__ bv,
              unsigned short* __restrict__ ws) {
  __shared__ unsigned short smem[32768];        // 64 KB: lA | lB; epilogue reuses
  unsigned short* lA = smem;
  unsigned short* lB = smem + 16384;

  const int x = blockIdx.x;
  const int b = (x >= 33) ? 3 : (x >= 22) ? 2 : (x >= 11) ? 1 : 0;
  const int j = x - 11 * b;
  const int z = blockIdx.z;
  const int n0 = blockIdx.y * 128;

  const unsigned short* W = WB + (size_t)z * (HID_ * HID_);
  const float* bias = (z == 0) ? bq : (z == 1) ? bk : bv;
  const float scale = (z == 0) ? QSCALE : 1.0f;

  const int tid = threadIdx.x;
  const int lane = tid & 63;
  const int wv = tid >> 6;
  const int l15 = lane & 15, quad = lane >> 4;
  const int wr = wv >> 1, wc = wv & 1;

  // staging: chunk = 4 rows x 128 cols (1 KB = 64 lanes x 16B). Wave wv owns
  // rows [wv*32, wv*32+32): 8 chunks each for A and B.
  const int crow = lane >> 4;               // row within chunk 0..3
  const int cg = lane & 15;                 // 16B group 0..15
  int offA[8], offB[8];
#pragma unroll
  for (int i = 0; i < 8; ++i) {
    int row = wv * 32 + i * 4 + crow;       // tile row 0..127
    int g = cg ^ (row & 15);                // swizzle on the global side
    int m = b * L_ + min(j * 128 + row, L_ - 1);
    offA[i] = m * HID_ + g * 8;
    offB[i] = (n0 + row) * HID_ + g * 8;
  }

  f32x4 acc[4][4];
#pragma unroll
  for (int i = 0; i < 4; i++)
#pragma unroll
    for (int jj = 0; jj < 4; jj++) acc[i][jj] = (f32x4){0.f, 0.f, 0.f, 0.f};

  for (int kt = 0; kt < HID_ / 128; ++kt) {   // 8 iters
    __syncthreads();
#pragma unroll
    for (int i = 0; i < 8; ++i) {
      GLOAD16(XB + offA[i] + kt * 128, &lA[(wv * 32 + i * 4) * 128]);
      GLOAD16(W + offB[i] + kt * 128, &lB[(wv * 32 + i * 4) * 128]);
    }
    __syncthreads();
#pragma unroll
    for (int kk = 0; kk < 4; ++kk) {
      bf16x8 af[4], bfr[4];
#pragma unroll
      for (int mi = 0; mi < 4; mi++) {
        int row = wr * 64 + mi * 16 + l15;
        af[mi] = *(const bf16x8*)&lA[row * 128 + (((kk * 4 + quad) ^ l15) * 8)];
      }
#pragma unroll
      for (int ni = 0; ni < 4; ni++) {
        int row = wc * 64 + ni * 16 + l15;
        bfr[ni] = *(const bf16x8*)&lB[row * 128 + (((kk * 4 + quad) ^ l15) * 8)];
      }
#pragma unroll
      for (int mi = 0; mi < 4; mi++)
#pragma unroll
        for (int ni = 0; ni < 4; ni++)
          acc[mi][ni] = __builtin_amdgcn_mfma_f32_16x16x32_bf16(af[mi], bfr[ni], acc[mi][ni], 0, 0, 0);
    }
  }

  // ---- epilogue: per-wave LDS transpose -> coalesced 16B stores ----
  __syncthreads();                         // all frag reads done before reuse
  unsigned short* lC = smem + wv * 4096;   // 8 KB per wave (64x64 bf16)
  const int h = blockIdx.y * 2 + wc;
  const int bh = b * 16 + h;
  const int lbase = j * 128 + wr * 64;

  if (z < 2) {
#pragma unroll
    for (int ni = 0; ni < 4; ni++) {
      int nl = ni * 16 + l15;
      float bn = bias[n0 + wc * 64 + nl];
      int gsn = nl >> 3, en = nl & 7;
#pragma unroll
      for (int mi = 0; mi < 4; mi++)
#pragma unroll
        for (int r = 0; r < 4; r++) {
          int ml = mi * 16 + quad * 4 + r;
          lC[ml * 64 + ((gsn ^ (ml & 7)) * 8) + en] = f2bf((acc[mi][ni][r] + bn) * scale);
        }
    }
    unsigned short* dst = ws + (z == 0 ? QW_OFF : KW_OFF) + (size_t)bh * (LPAD * 64);
#pragma unroll
    for (int i = 0; i < 8; ++i) {
      int ml = i * 8 + (lane >> 3);
      int g = lane & 7;
      bf16x8 v = *(const bf16x8*)&lC[ml * 64 + ((g ^ (ml & 7)) * 8)];
      int l = lbase + ml;                  // < LPAD always; pad rows = clamped copies
      *(bf16x8*)(dst + (size_t)l * 64 + g * 8) = v;
    }
  } else {
#pragma unroll
    for (int ni = 0; ni < 4; ni++) {
      int nl = ni * 16 + l15;
      float bn = bias[n0 + wc * 64 + nl];
#pragma unroll
      for (int mi = 0; mi < 4; mi++) {
        bf16x4 pk;
#pragma unroll
        for (int r = 0; r < 4; r++) pk[r] = (short)f2bf(acc[mi][ni][r] + bn);
        int gm = mi * 2 + (quad >> 1), h2 = quad & 1;
        *(bf16x4*)&lC[nl * 64 + ((gm ^ (nl & 7)) * 8) + h2 * 4] = pk;
      }
    }
    unsigned short* vt = ws + VT_OFF + (size_t)bh * (64 * LPAD);
#pragma unroll
    for (int i = 0; i < 8; ++i) {
      int nl = i * 8 + (lane >> 3);        // dd row of V^T
      int g = lane & 7;                    // m-group
      bf16x8 v = *(const bf16x8*)&lC[nl * 64 + ((g ^ (nl & 7)) * 8)];
      int l = lbase + g * 8;
      *(bf16x8*)(vt + (size_t)nl * LPAD + l) = v;
    }
  }
}

// ---------------- flash attention ----------------
// grid (88 = 11 q-tiles x 8 head_lo, 8 head_hi), 128 threads (2 waves).
// Wave owns 64 Q rows (4x16) -> block covers 128 rows. K-tile = 64 keys.
// Fatter Q per wave amortizes K/V LDS reads: 72 MFMA per 24 b128 reads.
// Softmax: p = exp2(qk' - SOFT_M2) (log2e*scale folded into Q; exact shift).
// Row sums via ones-MFMA (every output column = row sum, no shuffles).
__global__ __launch_bounds__(128)
void attn(const unsigned short* __restrict__ ws, float* __restrict__ out) {
  __shared__ unsigned short lK[64 * 64];   // [key][d] swizzled (8 KB)
  __shared__ unsigned short lV[64 * 64];   // [d][key] swizzled (8 KB)
  __shared__ unsigned short lP[2 * 64 * 64];  // per-wave P [64 q][64 k] (16 KB)

  const int tid = threadIdx.x;
  const int qt = blockIdx.x >> 3;                 // 0..10
  const int bh = blockIdx.y * 8 + (blockIdx.x & 7);
  const int b = bh >> 4, h = bh & 15;
  const int lane = tid & 63, wv = tid >> 6;
  const int l15 = lane & 15, quad = lane >> 4;

  const unsigned short* Qp = ws + QW_OFF + (size_t)bh * (LPAD * 64);
  const unsigned short* Kp = ws + KW_OFF + (size_t)bh * (LPAD * 64);
  const unsigned short* Vt = ws + VT_OFF + (size_t)bh * (64 * LPAD);

  // staging: wave 0 -> K tile, wave 1 -> V^T tile (8 GLOAD16 each)
  const int srow = lane >> 3;
  const int gsw = (lane & 7) ^ srow;
  const unsigned short* gbase = (wv == 0) ? Kp : Vt;
  unsigned short* ldst = (wv == 0) ? lK : lV;
  int goff[8];
#pragma unroll
  for (int t = 0; t < 8; ++t) {
    int row = 8 * t + srow;
    goff[t] = (wv == 0) ? (row * 64 + gsw * 8)     // K: key rows advance with kt
                        : (row * LPAD + gsw * 8);  // V^T: d rows, key cols advance
  }
  const int gstep = (wv == 0) ? (64 * 64) : 64;

  // Q fragments: 4 blocks of 16 rows (A/B index layout: idx=l15, k=quad*8+j)
  bf16x8 qf[4][2];
#pragma unroll
  for (int q2 = 0; q2 < 4; ++q2) {
    int qrow = qt * 128 + wv * 64 + q2 * 16 + l15;   // < LPAD (pad rows = clamped)
    qf[q2][0] = *(const bf16x8*)(Qp + (size_t)qrow * 64 + quad * 8);
    qf[q2][1] = *(const bf16x8*)(Qp + (size_t)qrow * 64 + 32 + quad * 8);
  }

  bf16x8 ones;
#pragma unroll
  for (int jj = 0; jj < 8; jj++) ones[jj] = (short)0x3F80;   // bf16 1.0

  const f32x4 minit = {-SOFT_M2, -SOFT_M2, -SOFT_M2, -SOFT_M2};

  f32x4 o[4][4], osum[4];
#pragma unroll
  for (int q2 = 0; q2 < 4; q2++) {
    osum[q2] = (f32x4){0.f, 0.f, 0.f, 0.f};
#pragma unroll
    for (int d = 0; d < 4; d++) o[q2][d] = (f32x4){0.f, 0.f, 0.f, 0.f};
  }

  unsigned short* lPw = lP + wv * 4096;

  const int NT = (L_ + 63) / 64;   // 22
  for (int kt = 0; kt < NT; ++kt) {
    const int s0 = kt * 64;
    __syncthreads();
#pragma unroll
    for (int t = 0; t < 8; ++t)
      GLOAD16(gbase + goff[t] + kt * gstep, ldst + t * 512);
    __syncthreads();

    // S^T = K Q^T : C row = key_local (quad*4+r), col = qrow (l15)
#pragma unroll
    for (int cb = 0; cb < 4; cb++) {
      int krow = cb * 16 + l15;
      bf16x8 kf0 = *(const bf16x8*)&lK[krow * 64 + ((quad ^ (l15 & 7)) * 8)];
      bf16x8 kf1 = *(const bf16x8*)&lK[krow * 64 + (((4 + quad) ^ (l15 & 7)) * 8)];
#pragma unroll
      for (int q2 = 0; q2 < 4; q2++) {
        f32x4 a = minit;
        a = __builtin_amdgcn_mfma_f32_16x16x32_bf16(kf0, qf[q2][0], a, 0, 0, 0);
        a = __builtin_amdgcn_mfma_f32_16x16x32_bf16(kf1, qf[q2][1], a, 0, 0, 0);
        if (s0 + 64 > L_) {
#pragma unroll
          for (int r = 0; r < 4; r++)
            if (s0 + cb * 16 + quad * 4 + r >= L_) a[r] = -1e30f;
        }
        u32x2 pk;
        pk[0] = pkbf(fexp2(a[0]), fexp2(a[1]));
        pk[1] = pkbf(fexp2(a[2]), fexp2(a[3]));
        int prow = q2 * 16 + l15;
        int gw = cb * 2 + (quad >> 1), h2 = quad & 1;
        *(u32x2*)&lPw[prow * 64 + ((gw ^ (l15 & 7)) * 8) + h2 * 4] = pk;
      }
    }

    // O += P V ; row sums via ones-MFMA on the same pipe
#pragma unroll
    for (int kk = 0; kk < 2; kk++) {
      bf16x8 pa[4];
#pragma unroll
      for (int q2 = 0; q2 < 4; q2++) {
        pa[q2] = *(const bf16x8*)&lPw[(q2 * 16 + l15) * 64 + (((kk * 4 + quad) ^ (l15 & 7)) * 8)];
        osum[q2] = __builtin_amdgcn_mfma_f32_16x16x32_bf16(pa[q2], ones, osum[q2], 0, 0, 0);
      }
#pragma unroll
      for (int d = 0; d < 4; d++) {
        int vrow = d * 16 + l15;
        bf16x8 vb = *(const bf16x8*)&lV[vrow * 64 + (((kk * 4 + quad) ^ (l15 & 7)) * 8)];
#pragma unroll
        for (int q2 = 0; q2 < 4; q2++)
          o[q2][d] = __builtin_amdgcn_mfma_f32_16x16x32_bf16(pa[q2], vb, o[q2][d], 0, 0, 0);
      }
    }
  }

  // normalize + store; osum cols identical -> inv is in-lane (no shuffles)
#pragma unroll
  for (int q2 = 0; q2 < 4; q2++) {
    float inv[4];
#pragma unroll
    for (int r = 0; r < 4; r++) inv[r] = 1.0f / osum[q2][r];
#pragma unroll
    for (int d = 0; d < 4; d++)
#pragma unroll
      for (int r = 0; r < 4; r++) {
        int l = qt * 128 + wv * 64 + q2 * 16 + quad * 4 + r;
        if (l < L_) {
          int dd = d * 16 + l15;
          out[((size_t)(b * L_ + l)) * HID_ + h * 64 + dd] = o[q2][d][r] * inv[r];
        }
      }
  }
}

// ---------------- launcher ----------------
extern "C" void kernel_launch(void* const* d_in, const int* in_sizes, int n_in,
                              void* d_out, int out_size, void* d_ws, size_t ws_size,
                              hipStream_t stream) {
  const float* hs = (const float*)d_in[0];
  const float* Wq = (const float*)d_in[1];
  const float* bq = (const float*)d_in[2];
  const float* Wk = (const float*)d_in[3];
  const float* bk = (const float*)d_in[4];
  const float* Wv = (const float*)d_in[5];
  const float* bv = (const float*)d_in[6];
  float* out = (float*)d_out;
  unsigned short* ws = (unsigned short*)d_ws;

  cvt_all<<<dim3((TOT4 + 255) / 256), 256, 0, stream>>>(hs, Wq, Wk, Wv, ws);

  qkv_gemm<<<dim3(44, 8, 3), 256, 0, stream>>>(ws + XB_OFF, ws + WB_OFF,
                                               bq, bk, bv, ws);

  attn<<<dim3(88, 8), 128, 0, stream>>>(ws, out);
}

// Round 7
// 193.985 us; speedup vs baseline: 1.3999x; 1.3999x over previous
//
#include <hip/hip_runtime.h>

// ---------------- problem constants ----------------
#define B_    4
#define L_    1370
#define NH_   16
#define D_    64
#define HID_  1024
#define M_    (B_ * L_)        // 5480
#define LPAD  1408             // padded rows/cols per head (multiple of 128)

// workspace layout (bf16 elements)
#define XB_OFF  0u                      // X bf16 [M_][1024]        = 5,611,520
#define WB_OFF  5611520u                // Wq|Wk|Wv bf16            = 3,145,728
#define QW_OFF  8757248u                // q  [bh][LPAD][64]        = 5,767,168
#define KW_OFF  14524416u               // k  [bh][LPAD][64]        = 5,767,168
#define VT_OFF  20291584u               // v^T [bh][64][LPAD]       = 5,767,168
// total 26,058,752 el = 52.1 MB

typedef __attribute__((ext_vector_type(8))) short bf16x8;
typedef __attribute__((ext_vector_type(4))) short bf16x4;
typedef __attribute__((ext_vector_type(4))) float f32x4;
typedef __attribute__((ext_vector_type(2))) unsigned int u32x2;

#define LOG2E   1.44269504089f
#define QSCALE  0.18033688011f    // 0.125 * log2(e), folded into Q at GEMM
#define SOFT_M2 14.4269504089f    // 10 * log2(e): exp(s-10) == exp2(qk' - SOFT_M2)

__device__ __forceinline__ unsigned short f2bf(float f) {
  unsigned int u = __builtin_bit_cast(unsigned int, f);
  u += 0x7FFFu + ((u >> 16) & 1u);
  return (unsigned short)(u >> 16);
}

__device__ __forceinline__ float fexp2(float x) {
#if __has_builtin(__builtin_amdgcn_exp2f)
  return __builtin_amdgcn_exp2f(x);
#else
  return exp2f(x);
#endif
}

__device__ __forceinline__ unsigned int pkbf(float a, float b) {
#if __has_builtin(__builtin_amdgcn_cvt_pk_bf16_f32)
  auto r = __builtin_amdgcn_cvt_pk_bf16_f32(a, b);   // a -> low16, b -> high16
  return __builtin_bit_cast(unsigned int, r);
#else
  return (unsigned int)f2bf(a) | ((unsigned int)f2bf(b) << 16);
#endif
}

// async global->LDS, 16B per lane; LDS dest = wave-uniform base + lane*16
#define GLOAD16(gp, lp)                                                    \
  __builtin_amdgcn_global_load_lds(                                        \
      (const __attribute__((address_space(1))) unsigned int*)(gp),         \
      (__attribute__((address_space(3))) unsigned int*)(lp), 16, 0, 0)

// ---------------- fp32 -> bf16 (X + Wq + Wk + Wv) ----------------
#define XN4 ((M_ * HID_) / 4)
#define WN4 ((HID_ * HID_) / 4)
#define TOT4 (XN4 + 3 * WN4)

__global__ void cvt_all(const float* __restrict__ hs,
                        const float* __restrict__ Wq,
                        const float* __restrict__ Wk,
                        const float* __restrict__ Wv,
                        unsigned short* __restrict__ ws) {
  int i4 = blockIdx.x * 256 + threadIdx.x;
  if (i4 >= TOT4) return;
  const float* src;
  unsigned short* dst;
  if (i4 < XN4) {
    src = hs + (size_t)i4 * 4;
    dst = ws + XB_OFF + (size_t)i4 * 4;
  } else {
    int j = i4 - XN4;
    int w = j >> 18;
    int jj = j & (WN4 - 1);
    src = (w == 0 ? Wq : w == 1 ? Wk : Wv) + (size_t)jj * 4;
    dst = ws + WB_OFF + (size_t)w * (HID_ * HID_) + (size_t)jj * 4;
  }
  float4 v = *(const float4*)src;
  bf16x4 o;
  o[0] = (short)f2bf(v.x); o[1] = (short)f2bf(v.y);
  o[2] = (short)f2bf(v.z); o[3] = (short)f2bf(v.w);
  *(bf16x4*)dst = o;
}

// ---------------- QKV projection GEMM ----------------
// grid (44 = 4 batches x 11 m-blocks, 8 n-blocks, 3 weights), 256 threads.
// 128x128 tile, BK=64 (round-5 config), DOUBLE-BUFFERED staging: loads for
// tile kt+1 are issued right after the barrier, compute runs on tile kt —
// the vmcnt(0) drain at the next barrier has a full compute phase to hide.
// LDS [row][64] unpadded, XOR swizzle g'=g^(row&7).
__global__ __launch_bounds__(256)
void qkv_gemm(const unsigned short* __restrict__ XB,
              const unsigned short* __restrict__ WB,
              const float* __restrict__ bq,
              const float* __restrict__ bk,
              const float* __restrict__ bv,
              unsigned short* __restrict__ ws) {
  __shared__ unsigned short smem[32768];   // 64 KB: 2 x (lA 8192 | lB 8192)

  const int x = blockIdx.x;
  const int b = (x >= 33) ? 3 : (x >= 22) ? 2 : (x >= 11) ? 1 : 0;
  const int j = x - 11 * b;
  const int z = blockIdx.z;
  const int n0 = blockIdx.y * 128;

  const unsigned short* W = WB + (size_t)z * (HID_ * HID_);
  const float* bias = (z == 0) ? bq : (z == 1) ? bk : bv;
  const float scale = (z == 0) ? QSCALE : 1.0f;

  const int tid = threadIdx.x;
  const int lane = tid & 63;
  const int wv = tid >> 6;
  const int l15 = lane & 15, quad = lane >> 4;
  const int wr = wv >> 1, wc = wv & 1;

  // staging: chunk = 8 rows x 64 cols (1 KB). Wave owns rows [wv*32,+32).
  const int srow = (lane >> 3);             // 0..7  (== row&7 for our rows)
  const int gsw = (lane & 7) ^ srow;        // swizzled 8-elem group
  int offA[4], offB[4];
#pragma unroll
  for (int i = 0; i < 4; ++i) {
    int row = wv * 32 + 8 * i + srow;       // tile row 0..127
    int m = b * L_ + min(j * 128 + row, L_ - 1);
    offA[i] = m * HID_ + gsw * 8;
    offB[i] = (n0 + row) * HID_ + gsw * 8;
  }

  f32x4 acc[4][4];
#pragma unroll
  for (int i = 0; i < 4; i++)
#pragma unroll
    for (int jj = 0; jj < 4; jj++) acc[i][jj] = (f32x4){0.f, 0.f, 0.f, 0.f};

  // prologue: stage tile 0 into buffer 0
#pragma unroll
  for (int i = 0; i < 4; ++i) {
    GLOAD16(XB + offA[i], &smem[(wv * 32 + 8 * i) * 64]);
    GLOAD16(W + offB[i], &smem[8192 + (wv * 32 + 8 * i) * 64]);
  }

  for (int kt = 0; kt < HID_ / 64; ++kt) {   // 16 iters
    __syncthreads();   // drains loads(kt); prior compute on the other buf done
    unsigned short* cur = smem + (kt & 1) * 16384;
    if (kt + 1 < HID_ / 64) {
      unsigned short* nxt = smem + ((kt + 1) & 1) * 16384;
      const int ko = (kt + 1) * 64;
#pragma unroll
      for (int i = 0; i < 4; ++i) {
        GLOAD16(XB + offA[i] + ko, &nxt[(wv * 32 + 8 * i) * 64]);
        GLOAD16(W + offB[i] + ko, &nxt[8192 + (wv * 32 + 8 * i) * 64]);
      }
    }
    const unsigned short* lA = cur;
    const unsigned short* lB = cur + 8192;
#pragma unroll
    for (int kk = 0; kk < 2; ++kk) {
      bf16x8 af[4], bfr[4];
#pragma unroll
      for (int mi = 0; mi < 4; mi++) {
        int row = wr * 64 + mi * 16 + l15;
        af[mi] = *(const bf16x8*)&lA[row * 64 + (((kk * 4 + quad) ^ (l15 & 7)) * 8)];
      }
#pragma unroll
      for (int ni = 0; ni < 4; ni++) {
        int row = wc * 64 + ni * 16 + l15;
        bfr[ni] = *(const bf16x8*)&lB[row * 64 + (((kk * 4 + quad) ^ (l15 & 7)) * 8)];
      }
#pragma unroll
      for (int mi = 0; mi < 4; mi++)
#pragma unroll
        for (int ni = 0; ni < 4; ni++)
          acc[mi][ni] = __builtin_amdgcn_mfma_f32_16x16x32_bf16(af[mi], bfr[ni], acc[mi][ni], 0, 0, 0);
    }
  }

  // ---- epilogue: per-wave LDS transpose -> coalesced 16B stores ----
  __syncthreads();                         // all frag reads done before reuse
  unsigned short* lC = smem + wv * 4096;   // 8 KB per wave (64x64 bf16)
  const int h = blockIdx.y * 2 + wc;
  const int bh = b * 16 + h;
  const int lbase = j * 128 + wr * 64;

  if (z < 2) {
#pragma unroll
    for (int ni = 0; ni < 4; ni++) {
      int nl = ni * 16 + l15;
      float bn = bias[n0 + wc * 64 + nl];
      int gsn = nl >> 3, en = nl & 7;
#pragma unroll
      for (int mi = 0; mi < 4; mi++)
#pragma unroll
        for (int r = 0; r < 4; r++) {
          int ml = mi * 16 + quad * 4 + r;
          lC[ml * 64 + ((gsn ^ (ml & 7)) * 8) + en] = f2bf((acc[mi][ni][r] + bn) * scale);
        }
    }
    unsigned short* dst = ws + (z == 0 ? QW_OFF : KW_OFF) + (size_t)bh * (LPAD * 64);
#pragma unroll
    for (int i = 0; i < 8; ++i) {
      int ml = i * 8 + (lane >> 3);
      int g = lane & 7;
      bf16x8 v = *(const bf16x8*)&lC[ml * 64 + ((g ^ (ml & 7)) * 8)];
      int l = lbase + ml;                  // < LPAD always; pad rows = clamped copies
      *(bf16x8*)(dst + (size_t)l * 64 + g * 8) = v;
    }
  } else {
#pragma unroll
    for (int ni = 0; ni < 4; ni++) {
      int nl = ni * 16 + l15;
      float bn = bias[n0 + wc * 64 + nl];
#pragma unroll
      for (int mi = 0; mi < 4; mi++) {
        bf16x4 pk;
#pragma unroll
        for (int r = 0; r < 4; r++) pk[r] = (short)f2bf(acc[mi][ni][r] + bn);
        int gm = mi * 2 + (quad >> 1), h2 = quad & 1;
        *(bf16x4*)&lC[nl * 64 + ((gm ^ (nl & 7)) * 8) + h2 * 4] = pk;
      }
    }
    unsigned short* vt = ws + VT_OFF + (size_t)bh * (64 * LPAD);
#pragma unroll
    for (int i = 0; i < 8; ++i) {
      int nl = i * 8 + (lane >> 3);        // dd row of V^T
      int g = lane & 7;                    // m-group
      bf16x8 v = *(const bf16x8*)&lC[nl * 64 + ((g ^ (nl & 7)) * 8)];
      int l = lbase + g * 8;
      *(bf16x8*)(vt + (size_t)nl * LPAD + l) = v;
    }
  }
}

// ---------------- flash attention ----------------
// grid (88 = 11 q-tiles x 8 head_lo, 8 head_hi), 256 threads (4 waves) —
// round-5 config (32 Q rows/wave), now with DOUBLE-BUFFERED K/V staging.
// Softmax: p = exp2(qk' - SOFT_M2) (log2e*scale folded into Q; exact shift).
// Row sums via ones-MFMA (every output column = row sum, no shuffles).
__global__ __launch_bounds__(256)
void attn(const unsigned short* __restrict__ ws, float* __restrict__ out) {
  __shared__ unsigned short lKV[2 * 8192];    // 32 KB: buf{0,1} x (K 4096 | V 4096)
  __shared__ unsigned short lP[4 * 32 * 64];  // 16 KB: per-wave P [32 q][64 k]

  const int tid = threadIdx.x;
  const int qt = blockIdx.x >> 3;                 // 0..10
  const int bh = blockIdx.y * 8 + (blockIdx.x & 7);
  const int b = bh >> 4, h = bh & 15;
  const int lane = tid & 63, wv = tid >> 6;
  const int l15 = lane & 15, quad = lane >> 4;

  const unsigned short* Qp = ws + QW_OFF + (size_t)bh * (LPAD * 64);
  const unsigned short* Kp = ws + KW_OFF + (size_t)bh * (LPAD * 64);
  const unsigned short* Vt = ws + VT_OFF + (size_t)bh * (64 * LPAD);

  // staging: waves 0,1 -> K halves; waves 2,3 -> V^T halves (4 GLOAD16 each)
  const int srow = lane >> 3;
  const int gsw = (lane & 7) ^ srow;
  const bool isK = (wv < 2);
  const int half = wv & 1;
  const unsigned short* gbase = isK ? Kp : Vt;
  const int lofs = (isK ? 0 : 4096) + half * 32 * 64;
  int goff[4];
#pragma unroll
  for (int t = 0; t < 4; ++t) {
    int row = half * 32 + 8 * t + srow;
    goff[t] = isK ? (row * 64 + gsw * 8)       // K: key rows advance with kt
                  : (row * LPAD + gsw * 8);    // V^T: d rows, key cols advance
  }
  const int gstep = isK ? (64 * 64) : 64;

  // Q fragments: 2 blocks of 16 rows (A/B index layout: idx=l15, k=quad*8+j)
  bf16x8 qf[2][2];
#pragma unroll
  for (int q2 = 0; q2 < 2; ++q2) {
    int qrow = qt * 128 + wv * 32 + q2 * 16 + l15;   // < LPAD
    qf[q2][0] = *(const bf16x8*)(Qp + (size_t)qrow * 64 + quad * 8);
    qf[q2][1] = *(const bf16x8*)(Qp + (size_t)qrow * 64 + 32 + quad * 8);
  }

  bf16x8 ones;
#pragma unroll
  for (int jj = 0; jj < 8; jj++) ones[jj] = (short)0x3F80;   // bf16 1.0

  const f32x4 minit = {-SOFT_M2, -SOFT_M2, -SOFT_M2, -SOFT_M2};

  f32x4 o[2][4], osum[2];
#pragma unroll
  for (int q2 = 0; q2 < 2; q2++) {
    osum[q2] = (f32x4){0.f, 0.f, 0.f, 0.f};
#pragma unroll
    for (int d = 0; d < 4; d++) o[q2][d] = (f32x4){0.f, 0.f, 0.f, 0.f};
  }

  unsigned short* lPw = lP + wv * 2048;

  const int NT = (L_ + 63) / 64;   // 22

  // prologue: stage tile 0 into buffer 0
#pragma unroll
  for (int t = 0; t < 4; ++t)
    GLOAD16(gbase + goff[t], lKV + lofs + t * 512);

  for (int kt = 0; kt < NT; ++kt) {
    const int s0 = kt * 64;
    __syncthreads();   // drains loads(kt); prior compute on other buf done
    const unsigned short* lK = lKV + (kt & 1) * 8192;
    const unsigned short* lV = lK + 4096;
    if (kt + 1 < NT) {
      unsigned short* nxt = lKV + ((kt + 1) & 1) * 8192 + lofs;
      const int go = (kt + 1) * gstep;
#pragma unroll
      for (int t = 0; t < 4; ++t)
        GLOAD16(gbase + goff[t] + go, nxt + t * 512);
    }

    // S^T = K Q^T : C row = key_local (quad*4+r), col = qrow (l15)
#pragma unroll
    for (int cb = 0; cb < 4; cb++) {
      int krow = cb * 16 + l15;
      bf16x8 kf0 = *(const bf16x8*)&lK[krow * 64 + ((quad ^ (l15 & 7)) * 8)];
      bf16x8 kf1 = *(const bf16x8*)&lK[krow * 64 + (((4 + quad) ^ (l15 & 7)) * 8)];
#pragma unroll
      for (int q2 = 0; q2 < 2; q2++) {
        f32x4 a = minit;
        a = __builtin_amdgcn_mfma_f32_16x16x32_bf16(kf0, qf[q2][0], a, 0, 0, 0);
        a = __builtin_amdgcn_mfma_f32_16x16x32_bf16(kf1, qf[q2][1], a, 0, 0, 0);
        if (s0 + 64 > L_) {
#pragma unroll
          for (int r = 0; r < 4; r++)
            if (s0 + cb * 16 + quad * 4 + r >= L_) a[r] = -1e30f;
        }
        u32x2 pk;
        pk[0] = pkbf(fexp2(a[0]), fexp2(a[1]));
        pk[1] = pkbf(fexp2(a[2]), fexp2(a[3]));
        int prow = q2 * 16 + l15;
        int gw = cb * 2 + (quad >> 1), h2 = quad & 1;
        *(u32x2*)&lPw[prow * 64 + ((gw ^ (l15 & 7)) * 8) + h2 * 4] = pk;
      }
    }

    // O += P V ; row sums via ones-MFMA on the same pipe
#pragma unroll
    for (int kk = 0; kk < 2; kk++) {
      bf16x8 pa[2];
#pragma unroll
      for (int q2 = 0; q2 < 2; q2++) {
        pa[q2] = *(const bf16x8*)&lPw[(q2 * 16 + l15) * 64 + (((kk * 4 + quad) ^ (l15 & 7)) * 8)];
        osum[q2] = __builtin_amdgcn_mfma_f32_16x16x32_bf16(pa[q2], ones, osum[q2], 0, 0, 0);
      }
#pragma unroll
      for (int d = 0; d < 4; d++) {
        int vrow = d * 16 + l15;
        bf16x8 vb = *(const bf16x8*)&lV[vrow * 64 + (((kk * 4 + quad) ^ (l15 & 7)) * 8)];
#pragma unroll
        for (int q2 = 0; q2 < 2; q2++)
          o[q2][d] = __builtin_amdgcn_mfma_f32_16x16x32_bf16(pa[q2], vb, o[q2][d], 0, 0, 0);
      }
    }
  }

  // normalize + store; osum cols identical -> inv is in-lane (no shuffles)
#pragma unroll
  for (int q2 = 0; q2 < 2; q2++) {
    float inv[4];
#pragma unroll
    for (int r = 0; r < 4; r++) inv[r] = 1.0f / osum[q2][r];
#pragma unroll
    for (int d = 0; d < 4; d++)
#pragma unroll
      for (int r = 0; r < 4; r++) {
        int l = qt * 128 + wv * 32 + q2 * 16 + quad * 4 + r;
        if (l < L_) {
          int dd = d * 16 + l15;
          out[((size_t)(b * L_ + l)) * HID_ + h * 64 + dd] = o[q2][d][r] * inv[r];
        }
      }
  }
}

// ---------------- launcher ----------------
extern "C" void kernel_launch(void* const* d_in, const int* in_sizes, int n_in,
                              void* d_out, int out_size, void* d_ws, size_t ws_size,
                              hipStream_t stream) {
  const float* hs = (const float*)d_in[0];
  const float* Wq = (const float*)d_in[1];
  const float* bq = (const float*)d_in[2];
  const float* Wk = (const float*)d_in[3];
  const float* bk = (const float*)d_in[4];
  const float* Wv = (const float*)d_in[5];
  const float* bv = (const float*)d_in[6];
  float* out = (float*)d_out;
  unsigned short* ws = (unsigned short*)d_ws;

  cvt_all<<<dim3((TOT4 + 255) / 256), 256, 0, stream>>>(hs, Wq, Wk, Wv, ws);

  qkv_gemm<<<dim3(44, 8, 3), 256, 0, stream>>>(ws + XB_OFF, ws + WB_OFF,
                                               bq, bk, bv, ws);

  attn<<<dim3(88, 8), 256, 0, stream>>>(ws, out);
}